// Round 1
// baseline (18318.372 us; speedup 1.0000x reference)
//
#include <hip/hip_runtime.h>
#include <stdint.h>

// ---------------- problem constants ----------------
#define TT 512
#define BB 256
#define HH 256
#define II 128
#define OUTD 128
#define EPSV 1e-5f

// ---------------- geometry ----------------
// 32 clusters x 8 batch rows, ONE workgroup (1024 thr / 16 waves) per cluster.
// Waves 0-7 : layer-1 GRU cell (x@Wih1 + h1@Whh1 -> h1), own weights in VGPRs.
// Waves 8-15: layer-2 GRU cell, lagged one step (h1@Wih2 + h2@Whh2 -> h2).
// h1/h2 handed over through double-buffered LDS; ONE __syncthreads per step.
// No inter-WG communication at all (the previous 4-CU pipeline spent ~5 us/step
// on system-scope ring traffic + vmcnt(0) drains + polls).
//
// Row-interleave: batch rows live in MFMA row-slots {0,1,4,5,8,9,12,13}
// (C layout row = qd*4 + reg, so valid rows sit at reg 0,1 for every qd) ->
// gate VALU per lane is halved; garbage slots stay zero and only affect
// unused C rows (C row m depends only on A row m).
#define NCL 32
#define RPC 8
#define HPAD 264    // LDS row stride (shorts); 528B rows, 16B-aligned frags

#define OFF_BNSUM    1024u
#define OFF_BNSQ     2048u
#define OFF_ZERO_END 3072u
#define OFF_H2SEQ    65536u
#define OFF_XBF      (OFF_H2SEQ + (unsigned)BB*TT*HH*2u)   // +64MB; xbf = 32MB

typedef short bf16x8 __attribute__((ext_vector_type(8)));
typedef short s16x4  __attribute__((ext_vector_type(4)));
typedef float f32x4  __attribute__((ext_vector_type(4)));

__device__ __forceinline__ short f2bf(float v) {
    unsigned u = __float_as_uint(v);
    u += 0x7fffu + ((u >> 16) & 1u);
    return (short)(u >> 16);
}
__device__ __forceinline__ float bf2f(short s) {
    return __uint_as_float(((unsigned)(unsigned short)s) << 16);
}
__device__ __forceinline__ bf16x8 ldfrag_f32(const float* __restrict__ p) {
    const float4* q = (const float4*)p;
    float4 a = q[0], b = q[1];
    bf16x8 f;
    f[0]=f2bf(a.x); f[1]=f2bf(a.y); f[2]=f2bf(a.z); f[3]=f2bf(a.w);
    f[4]=f2bf(b.x); f[5]=f2bf(b.y); f[6]=f2bf(b.z); f[7]=f2bf(b.w);
    return f;
}
__device__ __forceinline__ float sigm_f(float x) {
    // 1/(1+exp(-x)); exp overflow -> inf -> rcp = 0 (correct limit)
    float e = __expf(-x);
    return __builtin_amdgcn_rcpf(1.f + e);
}
__device__ __forceinline__ float tanh_f(float x) {
    float ax = fabsf(x);
    float e  = __expf(-2.f * ax);              // in (0,1]
    float t  = (1.f - e) * __builtin_amdgcn_rcpf(1.f + e);
    return copysignf(t, x);
}

// ---------------- x fp32 -> bf16 prepack ----------------
__global__ void cvt_x(const float* __restrict__ x, short* __restrict__ xbf, int n) {
    int i = (blockIdx.x * blockDim.x + threadIdx.x) * 4;
    if (i < n) {
        float4 v = *(const float4*)(x + i);
        s16x4 o; o[0]=f2bf(v.x); o[1]=f2bf(v.y); o[2]=f2bf(v.z); o[3]=f2bf(v.w);
        *(s16x4*)(xbf + i) = o;
    }
}

// ---------------- fused single-CU two-layer GRU ----------------
__global__ void __launch_bounds__(1024)
gru_fused(const short* __restrict__ xbf,
          const float* __restrict__ wih1, const float* __restrict__ whh1,
          const float* __restrict__ bih1, const float* __restrict__ bhh1,
          const float* __restrict__ wih2, const float* __restrict__ whh2,
          const float* __restrict__ bih2, const float* __restrict__ bhh2,
          char* __restrict__ ws)
{
    const int tid  = threadIdx.x;
    const int wave = tid >> 6;     // 0..15
    const int lane = tid & 63;
    const int qd   = lane >> 4;    // 0..3
    const int ln   = lane & 15;
    const int cl   = blockIdx.x;
    const int grow0= cl * RPC;

    float* bnsum = (float*)(ws + OFF_BNSUM);
    float* bnsq  = (float*)(ws + OFF_BNSQ);
    short* h2seq = (short*)(ws + OFF_H2SEQ);

    __shared__ __align__(16) short hb1[2][16][HPAD];
    __shared__ __align__(16) short hb2[2][16][HPAD];

    // zero both h buffers (garbage row-slots must stay 0 forever)
    {
        short* z1 = &hb1[0][0][0];
        short* z2 = &hb2[0][0][0];
        for (int i = tid; i < 2*16*HPAD; i += 1024) { z1[i] = 0; z2[i] = 0; }
    }

    if (wave < 8) {
        // ================= layer-1 group =================
        bf16x8 Wi[2][3][4], Wh[2][3][8];
        float bR[2], bZ[2], bNi[2], bNh[2];
        #pragma unroll
        for (int b2 = 0; b2 < 2; ++b2) {
            const int colg = (wave*2 + b2)*16 + ln;
            #pragma unroll
            for (int g = 0; g < 3; ++g) {
                const int grow = g*256 + colg;
                #pragma unroll
                for (int kc = 0; kc < 4; ++kc)
                    Wi[b2][g][kc] = ldfrag_f32(wih1 + grow*II + kc*32 + qd*8);
                #pragma unroll
                for (int kc = 0; kc < 8; ++kc)
                    Wh[b2][g][kc] = ldfrag_f32(whh1 + grow*HH + kc*32 + qd*8);
            }
            bR[b2]  = bih1[colg]       + bhh1[colg];
            bZ[b2]  = bih1[256 + colg] + bhh1[256 + colg];
            bNi[b2] = bih1[512 + colg];
            bNh[b2] = bhh1[512 + colg];
        }
        // A-slot ln holds batch row grow0 + (ln>>2)*2 + (ln&1)  (dup for garbage slots)
        const short* xr = xbf + (size_t)(grow0 + (ln>>2)*2 + (ln&1)) * (TT*II) + qd*8;
        bf16x8 xf[4];
        #pragma unroll
        for (int kc = 0; kc < 4; ++kc) xf[kc] = *(const bf16x8*)(xr + kc*32);
        float hold[2][2] = {{0.f,0.f},{0.f,0.f}};
        __syncthreads();

        for (int it = 0; it < TT + 1; ++it) {
            if (it < TT) {
                const int t  = it;
                const int rb = (t + 1) & 1;   // h1(t-1)
                const int wb = t & 1;         // h1(t)
                f32x4 aR[2], aZ[2], aNi[2], aNh[2];
                #pragma unroll
                for (int b2 = 0; b2 < 2; ++b2) {
                    aR[b2]  = f32x4{bR[b2],bR[b2],bR[b2],bR[b2]};
                    aZ[b2]  = f32x4{bZ[b2],bZ[b2],bZ[b2],bZ[b2]};
                    aNi[b2] = f32x4{bNi[b2],bNi[b2],bNi[b2],bNi[b2]};
                    aNh[b2] = f32x4{bNh[b2],bNh[b2],bNh[b2],bNh[b2]};
                }
                #pragma unroll
                for (int kc = 0; kc < 4; ++kc) {
                    bf16x8 a = xf[kc];
                    #pragma unroll
                    for (int b2 = 0; b2 < 2; ++b2) {
                        aR[b2]  = __builtin_amdgcn_mfma_f32_16x16x32_bf16(a, Wi[b2][0][kc], aR[b2], 0,0,0);
                        aZ[b2]  = __builtin_amdgcn_mfma_f32_16x16x32_bf16(a, Wi[b2][1][kc], aZ[b2], 0,0,0);
                        aNi[b2] = __builtin_amdgcn_mfma_f32_16x16x32_bf16(a, Wi[b2][2][kc], aNi[b2], 0,0,0);
                    }
                }
                // xf is dead now -> prefetch x(t+1); waits land next iteration
                if (t + 1 < TT) {
                    #pragma unroll
                    for (int kc = 0; kc < 4; ++kc)
                        xf[kc] = *(const bf16x8*)(xr + (size_t)(t+1)*II + kc*32);
                }
                #pragma unroll
                for (int kc = 0; kc < 8; ++kc) {
                    bf16x8 f = *(const bf16x8*)&hb1[rb][ln][kc*32 + qd*8];
                    #pragma unroll
                    for (int b2 = 0; b2 < 2; ++b2) {
                        aR[b2]  = __builtin_amdgcn_mfma_f32_16x16x32_bf16(f, Wh[b2][0][kc], aR[b2], 0,0,0);
                        aZ[b2]  = __builtin_amdgcn_mfma_f32_16x16x32_bf16(f, Wh[b2][1][kc], aZ[b2], 0,0,0);
                        aNh[b2] = __builtin_amdgcn_mfma_f32_16x16x32_bf16(f, Wh[b2][2][kc], aNh[b2], 0,0,0);
                    }
                }
                #pragma unroll
                for (int b2 = 0; b2 < 2; ++b2) {
                    const int colg = (wave*2 + b2)*16 + ln;
                    #pragma unroll
                    for (int r = 0; r < 2; ++r) {
                        float rg = sigm_f(aR[b2][r]);
                        float zg = sigm_f(aZ[b2][r]);
                        float ng = tanh_f(aNi[b2][r] + rg * aNh[b2][r]);
                        float h  = (1.f - zg) * ng + zg * hold[b2][r];
                        hold[b2][r] = h;
                        hb1[wb][qd*4 + r][colg] = f2bf(h);
                    }
                }
            }
            __syncthreads();
        }
    } else {
        // ================= layer-2 group (lags one step) =================
        const int wv = wave - 8;
        bf16x8 Wi[2][3][8], Wh[2][3][8];
        float bR[2], bZ[2], bNi[2], bNh[2];
        #pragma unroll
        for (int b2 = 0; b2 < 2; ++b2) {
            const int colg = (wv*2 + b2)*16 + ln;
            #pragma unroll
            for (int g = 0; g < 3; ++g) {
                const int grow = g*256 + colg;
                #pragma unroll
                for (int kc = 0; kc < 8; ++kc) {
                    Wi[b2][g][kc] = ldfrag_f32(wih2 + grow*HH + kc*32 + qd*8);
                    Wh[b2][g][kc] = ldfrag_f32(whh2 + grow*HH + kc*32 + qd*8);
                }
            }
            bR[b2]  = bih2[colg]       + bhh2[colg];
            bZ[b2]  = bih2[256 + colg] + bhh2[256 + colg];
            bNi[b2] = bih2[512 + colg];
            bNh[b2] = bhh2[512 + colg];
        }
        float hold[2][2] = {{0.f,0.f},{0.f,0.f}};
        float cbs[2] = {0.f, 0.f}, cbq[2] = {0.f, 0.f};
        __syncthreads();

        for (int it = 0; it < TT + 1; ++it) {
            if (it >= 1) {
                const int u   = it - 1;        // layer-2 step being computed
                const int rb1 = u & 1;         // hb1 buffer holding h1(u)
                const int rb2 = (u + 1) & 1;   // hb2 buffer holding h2(u-1)
                const int wb2 = u & 1;         // hb2 buffer receiving h2(u)
                f32x4 aR[2], aZ[2], aNi[2], aNh[2];
                #pragma unroll
                for (int b2 = 0; b2 < 2; ++b2) {
                    aR[b2]  = f32x4{bR[b2],bR[b2],bR[b2],bR[b2]};
                    aZ[b2]  = f32x4{bZ[b2],bZ[b2],bZ[b2],bZ[b2]};
                    aNi[b2] = f32x4{bNi[b2],bNi[b2],bNi[b2],bNi[b2]};
                    aNh[b2] = f32x4{bNh[b2],bNh[b2],bNh[b2],bNh[b2]};
                }
                #pragma unroll
                for (int kc = 0; kc < 8; ++kc) {
                    bf16x8 f = *(const bf16x8*)&hb1[rb1][ln][kc*32 + qd*8];
                    #pragma unroll
                    for (int b2 = 0; b2 < 2; ++b2) {
                        aR[b2]  = __builtin_amdgcn_mfma_f32_16x16x32_bf16(f, Wi[b2][0][kc], aR[b2], 0,0,0);
                        aZ[b2]  = __builtin_amdgcn_mfma_f32_16x16x32_bf16(f, Wi[b2][1][kc], aZ[b2], 0,0,0);
                        aNi[b2] = __builtin_amdgcn_mfma_f32_16x16x32_bf16(f, Wi[b2][2][kc], aNi[b2], 0,0,0);
                    }
                }
                #pragma unroll
                for (int kc = 0; kc < 8; ++kc) {
                    bf16x8 f = *(const bf16x8*)&hb2[rb2][ln][kc*32 + qd*8];
                    #pragma unroll
                    for (int b2 = 0; b2 < 2; ++b2) {
                        aR[b2]  = __builtin_amdgcn_mfma_f32_16x16x32_bf16(f, Wh[b2][0][kc], aR[b2], 0,0,0);
                        aZ[b2]  = __builtin_amdgcn_mfma_f32_16x16x32_bf16(f, Wh[b2][1][kc], aZ[b2], 0,0,0);
                        aNh[b2] = __builtin_amdgcn_mfma_f32_16x16x32_bf16(f, Wh[b2][2][kc], aNh[b2], 0,0,0);
                    }
                }
                #pragma unroll
                for (int b2 = 0; b2 < 2; ++b2) {
                    const int colg = (wv*2 + b2)*16 + ln;
                    #pragma unroll
                    for (int r = 0; r < 2; ++r) {
                        float rg = sigm_f(aR[b2][r]);
                        float zg = sigm_f(aZ[b2][r]);
                        float ng = tanh_f(aNi[b2][r] + rg * aNh[b2][r]);
                        float h  = (1.f - zg) * ng + zg * hold[b2][r];
                        hold[b2][r] = h;
                        short hs = f2bf(h);
                        hb2[wb2][qd*4 + r][colg] = hs;
                        h2seq[(size_t)(grow0 + qd*2 + r)*TT*HH + (size_t)u*HH + colg] = hs;
                        cbs[b2] += h;
                        cbq[b2] += h * h;
                    }
                }
            }
            __syncthreads();
        }
        #pragma unroll
        for (int b2 = 0; b2 < 2; ++b2) {
            const int colg = (wv*2 + b2)*16 + ln;
            atomicAdd(&bnsum[colg], cbs[b2]);
            atomicAdd(&bnsq[colg],  cbq[b2]);
        }
    }
}

// ---------------- BN finalize + hardtanh + temporal mean + FC ----------------
__global__ void gru_final(const char* __restrict__ ws,
                          const float* __restrict__ gamma, const float* __restrict__ beta,
                          const float* __restrict__ fcw, const float* __restrict__ fcb,
                          float* __restrict__ out)
{
    __shared__ float summ[HH];
    const int b = blockIdx.x, c = threadIdx.x;
    const float* bnsum = (const float*)(ws + OFF_BNSUM);
    const float* bnsq  = (const float*)(ws + OFF_BNSQ);
    const short* h2seq = (const short*)(ws + OFF_H2SEQ);

    const float inv = 1.f / (float)(BB * TT);
    float mean = bnsum[c] * inv;
    float var  = bnsq[c] * inv - mean * mean;
    float scale = rsqrtf(var + EPSV) * gamma[c];
    float shift = beta[c] - mean * scale;

    const short* p = h2seq + (size_t)b*TT*HH + c;
    float acc = 0.f;
    #pragma unroll 4
    for (int t = 0; t < TT; ++t) {
        float v = bf2f(p[t*HH]) * scale + shift;
        v = fminf(fmaxf(v, -2.f), 2.f);
        acc += v;
    }
    summ[c] = acc * (1.f / TT);
    __syncthreads();
    if (c < OUTD) {
        float d = fcb[c];
        const float* wr = fcw + c*HH;
        #pragma unroll 8
        for (int h = 0; h < HH; ++h) d += wr[h] * summ[h];
        out[b*OUTD + c] = d;
    }
}

extern "C" void kernel_launch(void* const* d_in, const int* in_sizes, int n_in,
                              void* d_out, int out_size, void* d_ws, size_t ws_size,
                              hipStream_t stream)
{
    const float* x    = (const float*)d_in[0];
    const float* wih1 = (const float*)d_in[1];
    const float* whh1 = (const float*)d_in[2];
    const float* bih1 = (const float*)d_in[3];
    const float* bhh1 = (const float*)d_in[4];
    const float* wih2 = (const float*)d_in[5];
    const float* whh2 = (const float*)d_in[6];
    const float* bih2 = (const float*)d_in[7];
    const float* bhh2 = (const float*)d_in[8];
    const float* gamma= (const float*)d_in[9];
    const float* beta = (const float*)d_in[10];
    const float* fcw  = (const float*)d_in[11];
    const float* fcb  = (const float*)d_in[12];
    char* ws = (char*)d_ws;

    // BN accumulators must start at 0
    (void)hipMemsetAsync(ws, 0, OFF_ZERO_END, stream);

    const int nx = BB*TT*II;
    hipLaunchKernelGGL(cvt_x, dim3(nx/4/256), dim3(256), 0, stream,
                       x, (short*)(ws + OFF_XBF), nx);

    // 32 independent single-CU clusters, 8 batch rows each
    hipLaunchKernelGGL(gru_fused, dim3(NCL), dim3(1024), 0, stream,
                       (const short*)(ws + OFF_XBF),
                       wih1, whh1, bih1, bhh1, wih2, whh2, bih2, bhh2, ws);

    hipLaunchKernelGGL(gru_final, dim3(BB), dim3(HH), 0, stream,
                       (const char*)ws, gamma, beta, fcw, fcb, (float*)d_out);
}

// Round 4
// 1869.947 us; speedup vs baseline: 9.7962x; 9.7962x over previous
//
#include <hip/hip_runtime.h>
#include <stdint.h>

// ---------------- problem constants ----------------
#define TT 512
#define BB 256
#define HH 256
#define II 128
#define OUTD 128
#define EPSV 1e-5f

// ---------------- geometry ----------------
// 32 clusters x 8 batch rows; 4 WGs (stages) of 512 thr per cluster, one WG/CU,
// __launch_bounds__(512,1) => 256 VGPR/wave, Whh/Wih fully register-resident.
//   M1: gi1 = x@Wih1^T (+biases), recurrence-free, free-runs ~24 steps ahead
//   A : h1 recurrence (Whh1 in regs; gi1 ring prefetch-1)
//   M2: gi2 = h1@Wih2^T (h1 ring, prefetch-2)
//   B : h2 recurrence (Whh2 in regs; gi2 ring prefetch-early; h2seq + BN)
// Row-interleave: batch rows live in MFMA C-slots {r=0,1 of every quadrant}
// (slot s <-> batch row (s>>2)*2 + (s&1)) -> 4 gate elems/lane, no divergence,
// garbage slots stay zero (zeroed LDS rows never written).
// Rings: system-scope relaxed atomics; counted s_waitcnt (never vmcnt(0) in
// loops); progress posted with one-iteration slack (post t => step t-2 stores
// complete). rz preacts cross rings as bf16 (sigmoid path), n as fp32 (tanh).
// Watchdog: every poll gives up after ~2^17 spins (~10ms) and proceeds --
// converts any residual deadlock into a finishing wrong-answer run with
// counters instead of a dead container.
#define NCL 32
#define RPC 8
#define RD1 32      // gi1 ring depth (steps)
#define RD2 16      // gi2 / h1 ring depth
#define HPAD 264    // LDS row stride (shorts)
#define SPIN_CAP (1 << 17)

#define P_M1 0
#define P_A  1
#define P_M2 2
#define P_B  3

// ---------------- workspace layout (bytes), total ~90 MB ----------------
#define OFF_PROG     0u
#define OFF_BNSUM    1024u
#define OFF_BNSQ     2048u
#define OFF_ZERO_END 3072u
#define OFF_GI1      65536u
#define GI_SLOT      16384u                       // rz bf16 8KB + n fp32 8KB
#define GI1_BYTES    ((unsigned)NCL*RD1*GI_SLOT)  // 16 MB
#define OFF_H1R      (OFF_GI1 + GI1_BYTES)
#define H1R_BYTES    ((unsigned)NCL*RD2*4096u)    // 2 MB
#define OFF_GI2      (OFF_H1R + H1R_BYTES)
#define GI2_BYTES    ((unsigned)NCL*RD2*GI_SLOT)  // 8 MB
#define OFF_H2SEQ    (OFF_GI2 + GI2_BYTES)        // 64 MB bf16 [t][b][h]

typedef short bf16x8 __attribute__((ext_vector_type(8)));
typedef float f32x4  __attribute__((ext_vector_type(4)));
typedef unsigned long long u64;

__device__ __forceinline__ short f2bf(float v) {
    unsigned u = __float_as_uint(v);
    u += 0x7fffu + ((u >> 16) & 1u);
    return (short)(u >> 16);
}
__device__ __forceinline__ float bf2f(short s) {
    return __uint_as_float(((unsigned)(unsigned short)s) << 16);
}
__device__ __forceinline__ float bf2f_lo(unsigned u) {
    return __uint_as_float(u << 16);
}
__device__ __forceinline__ float bf2f_hi(unsigned u) {
    return __uint_as_float(u & 0xffff0000u);
}
__device__ __forceinline__ unsigned pk2bf(float a, float b) {
    return (unsigned)(unsigned short)f2bf(a) | ((unsigned)(unsigned short)f2bf(b) << 16);
}
__device__ __forceinline__ bf16x8 ldfrag_f32(const float* __restrict__ p) {
    const float4* q = (const float4*)p;
    float4 a = q[0], b = q[1];
    bf16x8 f;
    f[0]=f2bf(a.x); f[1]=f2bf(a.y); f[2]=f2bf(a.z); f[3]=f2bf(a.w);
    f[4]=f2bf(b.x); f[5]=f2bf(b.y); f[6]=f2bf(b.z); f[7]=f2bf(b.w);
    return f;
}
__device__ __forceinline__ float sigm_f(float x) {
    float e = __expf(-x);
    return __builtin_amdgcn_rcpf(1.f + e);
}
__device__ __forceinline__ float tanh_f(float x) {
    float ax = fabsf(x);
    float e  = __expf(-2.f * ax);
    float t  = (1.f - e) * __builtin_amdgcn_rcpf(1.f + e);
    return copysignf(t, x);
}
__device__ __forceinline__ void poll_ge(const unsigned* p, int tgt) {
    if (tgt <= 0) return;
    int spins = 0;
    while ((int)__hip_atomic_load((unsigned*)p, __ATOMIC_RELAXED, __HIP_MEMORY_SCOPE_SYSTEM) < tgt) {
        __builtin_amdgcn_s_sleep(2);
        if (++spins > SPIN_CAP) break;       // watchdog: proceed, surface as bad data
    }
    asm volatile("" ::: "memory");
}
__device__ __forceinline__ void poll2_ge(const unsigned* p1, int t1, const unsigned* p2, int t2) {
    int spins = 0;
    for (;;) {
        int a = (int)__hip_atomic_load((unsigned*)p1, __ATOMIC_RELAXED, __HIP_MEMORY_SCOPE_SYSTEM);
        int b = (int)__hip_atomic_load((unsigned*)p2, __ATOMIC_RELAXED, __HIP_MEMORY_SCOPE_SYSTEM);
        if (a >= t1 && b >= t2) break;
        __builtin_amdgcn_s_sleep(2);
        if (++spins > SPIN_CAP) break;       // watchdog
    }
    asm volatile("" ::: "memory");
}
__device__ __forceinline__ void post_prog(unsigned* p, int v) {
    __hip_atomic_store(p, (unsigned)v, __ATOMIC_RELAXED, __HIP_MEMORY_SCOPE_SYSTEM);
}
__device__ __forceinline__ unsigned ld_u32_coh(const unsigned* p) {
    return __hip_atomic_load((unsigned*)p, __ATOMIC_RELAXED, __HIP_MEMORY_SCOPE_SYSTEM);
}
__device__ __forceinline__ void st_u32_coh(unsigned* p, unsigned v) {
    __hip_atomic_store(p, v, __ATOMIC_RELAXED, __HIP_MEMORY_SCOPE_SYSTEM);
}
__device__ __forceinline__ u64 ld_u64_coh(const u64* p) {
    return __hip_atomic_load((u64*)p, __ATOMIC_RELAXED, __HIP_MEMORY_SCOPE_SYSTEM);
}
__device__ __forceinline__ void st_u64_coh(u64* p, u64 v) {
    __hip_atomic_store(p, v, __ATOMIC_RELAXED, __HIP_MEMORY_SCOPE_SYSTEM);
}
#define CFENCE() asm volatile("" ::: "memory")

// =============== persistent 4-stage pipeline ===============
__global__ void __launch_bounds__(512, 1)
gru_pipe(const float* __restrict__ x,
         const float* __restrict__ wih1, const float* __restrict__ whh1,
         const float* __restrict__ bih1, const float* __restrict__ bhh1,
         const float* __restrict__ wih2, const float* __restrict__ whh2,
         const float* __restrict__ bih2, const float* __restrict__ bhh2,
         char* __restrict__ ws)
{
    const int tid = threadIdx.x, wave = tid >> 6, lane = tid & 63;
    const int qd = lane >> 4, ln = lane & 15;
    const int stage = blockIdx.x & 3;
    const int cl    = blockIdx.x >> 2;
    const int grow0 = cl * RPC;

    unsigned* prog = (unsigned*)(ws + OFF_PROG) + cl * 4;
    short* h2seq = (short*)(ws + OFF_H2SEQ);

    __shared__ __align__(16) short hb[2][16][HPAD];
    {   // zero both buffers; garbage row-slots must stay 0 forever
        short* z = &hb[0][0][0];
        for (int i = tid; i < 2*16*HPAD; i += 512) z[i] = 0;
    }
    __syncthreads();

    if (stage == 0) {
        // ================= M1: gi1 producer (free-running) =================
        bf16x8 Wi[2][3][4]; f32x4 cinit[2][3];
        #pragma unroll
        for (int b2 = 0; b2 < 2; ++b2)
        #pragma unroll
        for (int g = 0; g < 3; ++g) {
            const int grow = g*256 + (wave*2 + b2)*16 + ln;
            #pragma unroll
            for (int kc = 0; kc < 4; ++kc)
                Wi[b2][g][kc] = ldfrag_f32(wih1 + grow*II + kc*32 + qd*8);
            float c0 = bih1[grow] + (g < 2 ? bhh1[grow] : 0.f);
            cinit[b2][g] = f32x4{c0, c0, c0, c0};
        }
        // A-slot ln -> batch row (ln>>2)*2 + (ln&1); garbage slots duplicate
        const float* xr = x + (size_t)(grow0 + (ln>>2)*2 + (ln&1)) * (TT*II) + qd*8;
        float4 xp[8];
        #pragma unroll
        for (int kc = 0; kc < 4; ++kc) {
            xp[2*kc]   = *(const float4*)(xr + kc*32);
            xp[2*kc+1] = *(const float4*)(xr + kc*32 + 4);
        }

        for (int t = 0; t < TT; ++t) {
            if (tid == 0 && t >= 2) post_prog(&prog[P_M1], t);
            if ((t & 7) == 0) poll_ge(&prog[P_A], t - 24);    // gi1 ring backpressure
            CFENCE();
            bf16x8 a[4];
            #pragma unroll
            for (int kc = 0; kc < 4; ++kc) {
                float4 u = xp[2*kc], v = xp[2*kc+1];
                bf16x8 f;
                f[0]=f2bf(u.x); f[1]=f2bf(u.y); f[2]=f2bf(u.z); f[3]=f2bf(u.w);
                f[4]=f2bf(v.x); f[5]=f2bf(v.y); f[6]=f2bf(v.z); f[7]=f2bf(v.w);
                a[kc] = f;
            }
            if (t + 1 < TT) {
                const float* xn = xr + (size_t)(t+1)*II;
                #pragma unroll
                for (int kc = 0; kc < 4; ++kc) {
                    xp[2*kc]   = *(const float4*)(xn + kc*32);
                    xp[2*kc+1] = *(const float4*)(xn + kc*32 + 4);
                }
            }
            CFENCE();
            f32x4 acc[2][3];
            #pragma unroll
            for (int b2 = 0; b2 < 2; ++b2)
            #pragma unroll
            for (int g = 0; g < 3; ++g) acc[b2][g] = cinit[b2][g];
            #pragma unroll
            for (int kc = 0; kc < 4; ++kc)
            #pragma unroll
            for (int b2 = 0; b2 < 2; ++b2)
            #pragma unroll
            for (int g = 0; g < 3; ++g)
                acc[b2][g] = __builtin_amdgcn_mfma_f32_16x16x32_bf16(a[kc], Wi[b2][g][kc], acc[b2][g], 0, 0, 0);
            CFENCE();
            char* slot = ws + OFF_GI1 + ((size_t)cl*RD1 + (t & (RD1-1)))*GI_SLOT;
            unsigned* rz = (unsigned*)slot;
            u64* nn = (u64*)(slot + 8192);
            #pragma unroll
            for (int b2 = 0; b2 < 2; ++b2) {
                const int tile = wave*2 + b2;
                st_u32_coh(rz + (tile*2 + 0)*64 + lane, pk2bf(acc[b2][0][0], acc[b2][0][1]));
                st_u32_coh(rz + (tile*2 + 1)*64 + lane, pk2bf(acc[b2][1][0], acc[b2][1][1]));
                union { float f[2]; u64 u; } np;
                np.f[0] = acc[b2][2][0]; np.f[1] = acc[b2][2][1];
                st_u64_coh(nn + tile*64 + lane, np.u);
            }
            asm volatile("s_waitcnt vmcnt(14)" ::: "memory");  // leaves {8 x-loads, 6 stores}
            __builtin_amdgcn_sched_barrier(0);
            __builtin_amdgcn_s_barrier();
        }
        __syncthreads();
        if (tid == 0) post_prog(&prog[P_M1], 1000000);

    } else if (stage == 1) {
        // ================= A: layer-1 recurrence =================
        bf16x8 Wh[2][3][8]; float bnn[2];
        #pragma unroll
        for (int b2 = 0; b2 < 2; ++b2) {
            const int colg = (wave*2 + b2)*16 + ln;
            #pragma unroll
            for (int g = 0; g < 3; ++g)
                #pragma unroll
                for (int kc = 0; kc < 8; ++kc)
                    Wh[b2][g][kc] = ldfrag_f32(whh1 + (g*256 + colg)*HH + kc*32 + qd*8);
            bnn[b2] = bhh1[512 + colg];
        }
        float hold[2][2] = {{0.f,0.f},{0.f,0.f}};
        unsigned pr0, pr1, pz0, pz1; u64 pn0, pn1;
        const int tile0 = wave*2, tile1 = wave*2 + 1;

        // prologue: gi1(0)
        poll_ge(&prog[P_M1], 2);
        {
            char* slot = ws + OFF_GI1 + (size_t)cl*RD1*GI_SLOT;
            const unsigned* rz = (const unsigned*)slot;
            const u64* nn = (const u64*)(slot + 8192);
            pr0 = ld_u32_coh(rz + (tile0*2+0)*64 + lane);
            pz0 = ld_u32_coh(rz + (tile0*2+1)*64 + lane);
            pn0 = ld_u64_coh(nn + tile0*64 + lane);
            pr1 = ld_u32_coh(rz + (tile1*2+0)*64 + lane);
            pz1 = ld_u32_coh(rz + (tile1*2+1)*64 + lane);
            pn1 = ld_u64_coh(nn + tile1*64 + lane);
        }

        for (int t = 0; t < TT; ++t) {
            if (tid == 0 && t >= 2) post_prog(&prog[P_A], t);
            if ((t & 7) == 0) poll2_ge(&prog[P_M1], t + 10, &prog[P_M2], t - 9);
            CFENCE();
            f32x4 aR[2], aZ[2], aN[2]; float gn[2][2];
            aR[0] = f32x4{bf2f_lo(pr0), bf2f_hi(pr0), 0.f, 0.f};
            aZ[0] = f32x4{bf2f_lo(pz0), bf2f_hi(pz0), 0.f, 0.f};
            aR[1] = f32x4{bf2f_lo(pr1), bf2f_hi(pr1), 0.f, 0.f};
            aZ[1] = f32x4{bf2f_lo(pz1), bf2f_hi(pz1), 0.f, 0.f};
            { union { u64 u; float f[2]; } c; c.u = pn0; gn[0][0]=c.f[0]; gn[0][1]=c.f[1];
              c.u = pn1; gn[1][0]=c.f[0]; gn[1][1]=c.f[1]; }
            aN[0] = f32x4{bnn[0], bnn[0], 0.f, 0.f};
            aN[1] = f32x4{bnn[1], bnn[1], 0.f, 0.f};
            if (t + 1 < TT) {   // prefetch gi1(t+1); latency hides under MFMA+gates
                char* slot = ws + OFF_GI1 + ((size_t)cl*RD1 + ((t+1) & (RD1-1)))*GI_SLOT;
                const unsigned* rz = (const unsigned*)slot;
                const u64* nn = (const u64*)(slot + 8192);
                pr0 = ld_u32_coh(rz + (tile0*2+0)*64 + lane);
                pz0 = ld_u32_coh(rz + (tile0*2+1)*64 + lane);
                pn0 = ld_u64_coh(nn + tile0*64 + lane);
                pr1 = ld_u32_coh(rz + (tile1*2+0)*64 + lane);
                pz1 = ld_u32_coh(rz + (tile1*2+1)*64 + lane);
                pn1 = ld_u64_coh(nn + tile1*64 + lane);
            }
            CFENCE();
            const int rb = (t + 1) & 1, wb = t & 1;
            #pragma unroll
            for (int kc = 0; kc < 8; ++kc) {
                bf16x8 f = *(const bf16x8*)&hb[rb][ln][kc*32 + qd*8];
                aR[0] = __builtin_amdgcn_mfma_f32_16x16x32_bf16(f, Wh[0][0][kc], aR[0], 0,0,0);
                aR[1] = __builtin_amdgcn_mfma_f32_16x16x32_bf16(f, Wh[1][0][kc], aR[1], 0,0,0);
                aZ[0] = __builtin_amdgcn_mfma_f32_16x16x32_bf16(f, Wh[0][1][kc], aZ[0], 0,0,0);
                aZ[1] = __builtin_amdgcn_mfma_f32_16x16x32_bf16(f, Wh[1][1][kc], aZ[1], 0,0,0);
                aN[0] = __builtin_amdgcn_mfma_f32_16x16x32_bf16(f, Wh[0][2][kc], aN[0], 0,0,0);
                aN[1] = __builtin_amdgcn_mfma_f32_16x16x32_bf16(f, Wh[1][2][kc], aN[1], 0,0,0);
            }
            CFENCE();
            unsigned* h1slot = (unsigned*)(ws + OFF_H1R + ((size_t)cl*RD2 + (t & (RD2-1)))*4096u);
            #pragma unroll
            for (int b2 = 0; b2 < 2; ++b2) {
                const int colg = (wave*2 + b2)*16 + ln;
                unsigned pk = 0;
                #pragma unroll
                for (int r = 0; r < 2; ++r) {
                    float rg = sigm_f(aR[b2][r]);
                    float zg = sigm_f(aZ[b2][r]);
                    float ng = tanh_f(gn[b2][r] + rg * aN[b2][r]);
                    float h  = (1.f - zg)*ng + zg*hold[b2][r];
                    hold[b2][r] = h;
                    short hs = f2bf(h);
                    hb[wb][qd*4 + r][colg] = hs;
                    pk |= (unsigned)(unsigned short)hs << (16*r);
                }
                st_u32_coh(h1slot + colg*4 + qd, pk);
            }
            asm volatile("s_waitcnt vmcnt(8) lgkmcnt(0)" ::: "memory");  // leaves {6 ld, 2 st}
            __builtin_amdgcn_sched_barrier(0);
            __builtin_amdgcn_s_barrier();
        }
        __syncthreads();
        if (tid == 0) post_prog(&prog[P_A], 1000000);

    } else if (stage == 2) {
        // ================= M2: gi2 = h1 @ Wih2^T =================
        bf16x8 Wi[2][3][8]; float c0s[2][3];
        #pragma unroll
        for (int b2 = 0; b2 < 2; ++b2)
        #pragma unroll
        for (int g = 0; g < 3; ++g) {
            const int grow = g*256 + (wave*2 + b2)*16 + ln;
            #pragma unroll
            for (int kc = 0; kc < 8; ++kc)
                Wi[b2][g][kc] = ldfrag_f32(wih2 + grow*HH + kc*32 + qd*8);
            c0s[b2][g] = bih2[grow] + (g < 2 ? bhh2[grow] : 0.f);
        }
        const int base = (tid & 1) * 8, pcol = tid >> 1;
        u64 vcur;

        // prologue: h1(0) -> hb[0]; preload h1(1)
        poll_ge(&prog[P_A], 2);
        {
            const u64* h1s = (const u64*)(ws + OFF_H1R + (size_t)cl*RD2*4096u);
            u64 v = ld_u64_coh(h1s + tid);
            unsigned lo = (unsigned)v, hi = (unsigned)(v >> 32);
            hb[0][base + 0][pcol] = (short)lo;
            hb[0][base + 1][pcol] = (short)(lo >> 16);
            hb[0][base + 4][pcol] = (short)hi;
            hb[0][base + 5][pcol] = (short)(hi >> 16);
        }
        poll_ge(&prog[P_A], 3);
        vcur = ld_u64_coh((const u64*)(ws + OFF_H1R + ((size_t)cl*RD2 + 1)*4096u) + tid);
        __syncthreads();

        for (int u = 0; u < TT; ++u) {
            if (tid == 0 && u >= 2) post_prog(&prog[P_M2], u);
            if ((u & 1) == 0) poll2_ge(&prog[P_A], u + 5, &prog[P_B], u - 13);
            CFENCE();
            // unpack h1(u+1) into hb[(u+1)&1] (loaded one iter ago)
            if (u + 1 < TT) {
                unsigned lo = (unsigned)vcur, hi = (unsigned)(vcur >> 32);
                hb[(u+1) & 1][base + 0][pcol] = (short)lo;
                hb[(u+1) & 1][base + 1][pcol] = (short)(lo >> 16);
                hb[(u+1) & 1][base + 4][pcol] = (short)hi;
                hb[(u+1) & 1][base + 5][pcol] = (short)(hi >> 16);
            }
            if (u + 2 < TT)
                vcur = ld_u64_coh((const u64*)(ws + OFF_H1R + ((size_t)cl*RD2 + ((u+2) & (RD2-1)))*4096u) + tid);
            CFENCE();
            f32x4 acc[2][3];
            #pragma unroll
            for (int b2 = 0; b2 < 2; ++b2)
            #pragma unroll
            for (int g = 0; g < 3; ++g) {
                float c0 = c0s[b2][g];
                acc[b2][g] = f32x4{c0, c0, c0, c0};
            }
            #pragma unroll
            for (int kc = 0; kc < 8; ++kc) {
                bf16x8 f = *(const bf16x8*)&hb[u & 1][ln][kc*32 + qd*8];
                #pragma unroll
                for (int b2 = 0; b2 < 2; ++b2)
                #pragma unroll
                for (int g = 0; g < 3; ++g)
                    acc[b2][g] = __builtin_amdgcn_mfma_f32_16x16x32_bf16(f, Wi[b2][g][kc], acc[b2][g], 0, 0, 0);
            }
            CFENCE();
            char* slot = ws + OFF_GI2 + ((size_t)cl*RD2 + (u & (RD2-1)))*GI_SLOT;
            unsigned* rz = (unsigned*)slot;
            u64* nn = (u64*)(slot + 8192);
            #pragma unroll
            for (int b2 = 0; b2 < 2; ++b2) {
                const int tile = wave*2 + b2;
                st_u32_coh(rz + (tile*2 + 0)*64 + lane, pk2bf(acc[b2][0][0], acc[b2][0][1]));
                st_u32_coh(rz + (tile*2 + 1)*64 + lane, pk2bf(acc[b2][1][0], acc[b2][1][1]));
                union { float f[2]; u64 u; } np;
                np.f[0] = acc[b2][2][0]; np.f[1] = acc[b2][2][1];
                st_u64_coh(nn + tile*64 + lane, np.u);
            }
            asm volatile("s_waitcnt vmcnt(7) lgkmcnt(0)" ::: "memory");  // leaves {1 ld, 6 st}
            __builtin_amdgcn_sched_barrier(0);
            __builtin_amdgcn_s_barrier();
        }
        __syncthreads();
        if (tid == 0) post_prog(&prog[P_M2], 1000000);

    } else {
        // ================= B: layer-2 recurrence + h2seq + BN =================
        bf16x8 Wh[2][3][8]; float bnn[2];
        #pragma unroll
        for (int b2 = 0; b2 < 2; ++b2) {
            const int colg = (wave*2 + b2)*16 + ln;
            #pragma unroll
            for (int g = 0; g < 3; ++g)
                #pragma unroll
                for (int kc = 0; kc < 8; ++kc)
                    Wh[b2][g][kc] = ldfrag_f32(whh2 + (g*256 + colg)*HH + kc*32 + qd*8);
            bnn[b2] = bhh2[512 + colg];
        }
        float* bnsum = (float*)(ws + OFF_BNSUM);
        float* bnsq  = (float*)(ws + OFF_BNSQ);
        float hold[2][2] = {{0.f,0.f},{0.f,0.f}};
        float cbs[2] = {0.f, 0.f}, cbq[2] = {0.f, 0.f};
        unsigned pr0, pr1, pz0, pz1; u64 pn0, pn1;
        const int tile0 = wave*2, tile1 = wave*2 + 1;

        // prologue: gi2(0)
        poll_ge(&prog[P_M2], 2);
        {
            char* slot = ws + OFF_GI2 + (size_t)cl*RD2*GI_SLOT;
            const unsigned* rz = (const unsigned*)slot;
            const u64* nn = (const u64*)(slot + 8192);
            pr0 = ld_u32_coh(rz + (tile0*2+0)*64 + lane);
            pz0 = ld_u32_coh(rz + (tile0*2+1)*64 + lane);
            pn0 = ld_u64_coh(nn + tile0*64 + lane);
            pr1 = ld_u32_coh(rz + (tile1*2+0)*64 + lane);
            pz1 = ld_u32_coh(rz + (tile1*2+1)*64 + lane);
            pn1 = ld_u64_coh(nn + tile1*64 + lane);
        }
        __syncthreads();

        for (int v = 0; v < TT; ++v) {
            if (tid == 0 && v >= 2) post_prog(&prog[P_B], v);
            if ((v & 1) == 0) poll_ge(&prog[P_M2], v + 4);
            CFENCE();
            f32x4 aR[2], aZ[2], aN[2]; float gn[2][2];
            aR[0] = f32x4{bf2f_lo(pr0), bf2f_hi(pr0), 0.f, 0.f};
            aZ[0] = f32x4{bf2f_lo(pz0), bf2f_hi(pz0), 0.f, 0.f};
            aR[1] = f32x4{bf2f_lo(pr1), bf2f_hi(pr1), 0.f, 0.f};
            aZ[1] = f32x4{bf2f_lo(pz1), bf2f_hi(pz1), 0.f, 0.f};
            { union { u64 u; float f[2]; } c; c.u = pn0; gn[0][0]=c.f[0]; gn[0][1]=c.f[1];
              c.u = pn1; gn[1][0]=c.f[0]; gn[1][1]=c.f[1]; }
            aN[0] = f32x4{bnn[0], bnn[0], 0.f, 0.f};
            aN[1] = f32x4{bnn[1], bnn[1], 0.f, 0.f};
            if (v + 1 < TT) {   // early reload; latency hides under MFMA+gates
                char* slot = ws + OFF_GI2 + ((size_t)cl*RD2 + ((v+1) & (RD2-1)))*GI_SLOT;
                const unsigned* rz = (const unsigned*)slot;
                const u64* nn = (const u64*)(slot + 8192);
                pr0 = ld_u32_coh(rz + (tile0*2+0)*64 + lane);
                pz0 = ld_u32_coh(rz + (tile0*2+1)*64 + lane);
                pn0 = ld_u64_coh(nn + tile0*64 + lane);
                pr1 = ld_u32_coh(rz + (tile1*2+0)*64 + lane);
                pz1 = ld_u32_coh(rz + (tile1*2+1)*64 + lane);
                pn1 = ld_u64_coh(nn + tile1*64 + lane);
            }
            CFENCE();
            const int rb = (v + 1) & 1, wb = v & 1;
            #pragma unroll
            for (int kc = 0; kc < 8; ++kc) {
                bf16x8 f = *(const bf16x8*)&hb[rb][ln][kc*32 + qd*8];
                aR[0] = __builtin_amdgcn_mfma_f32_16x16x32_bf16(f, Wh[0][0][kc], aR[0], 0,0,0);
                aR[1] = __builtin_amdgcn_mfma_f32_16x16x32_bf16(f, Wh[1][0][kc], aR[1], 0,0,0);
                aZ[0] = __builtin_amdgcn_mfma_f32_16x16x32_bf16(f, Wh[0][1][kc], aZ[0], 0,0,0);
                aZ[1] = __builtin_amdgcn_mfma_f32_16x16x32_bf16(f, Wh[1][1][kc], aZ[1], 0,0,0);
                aN[0] = __builtin_amdgcn_mfma_f32_16x16x32_bf16(f, Wh[0][2][kc], aN[0], 0,0,0);
                aN[1] = __builtin_amdgcn_mfma_f32_16x16x32_bf16(f, Wh[1][2][kc], aN[1], 0,0,0);
            }
            CFENCE();
            #pragma unroll
            for (int b2 = 0; b2 < 2; ++b2) {
                const int colg = (wave*2 + b2)*16 + ln;
                #pragma unroll
                for (int r = 0; r < 2; ++r) {
                    float rg = sigm_f(aR[b2][r]);
                    float zg = sigm_f(aZ[b2][r]);
                    float ng = tanh_f(gn[b2][r] + rg * aN[b2][r]);
                    float h  = (1.f - zg)*ng + zg*hold[b2][r];
                    hold[b2][r] = h;
                    cbs[b2] += h; cbq[b2] += h*h;
                    short hs = f2bf(h);
                    hb[wb][qd*4 + r][colg] = hs;
                    h2seq[((size_t)v*BB + grow0 + qd*2 + r)*HH + colg] = hs;
                }
            }
            asm volatile("s_waitcnt vmcnt(10) lgkmcnt(0)" ::: "memory");  // leaves {6 ld, 4 st}
            __builtin_amdgcn_sched_barrier(0);
            __builtin_amdgcn_s_barrier();
        }
        #pragma unroll
        for (int b2 = 0; b2 < 2; ++b2) {
            const int colg = (wave*2 + b2)*16 + ln;
            atomicAdd(&bnsum[colg], cbs[b2]);
            atomicAdd(&bnsq[colg],  cbq[b2]);
        }
        __syncthreads();
        if (tid == 0) post_prog(&prog[P_B], 1000000);
    }
}

// ---------------- BN finalize + hardtanh + temporal mean + FC ----------------
__global__ void gru_final(const char* __restrict__ ws,
                          const float* __restrict__ gamma, const float* __restrict__ beta,
                          const float* __restrict__ fcw, const float* __restrict__ fcb,
                          float* __restrict__ out)
{
    __shared__ float summ[HH];
    const int b = blockIdx.x, c = threadIdx.x;
    const float* bnsum = (const float*)(ws + OFF_BNSUM);
    const float* bnsq  = (const float*)(ws + OFF_BNSQ);
    const short* h2seq = (const short*)(ws + OFF_H2SEQ);

    const float inv = 1.f / (float)(BB * TT);
    float mean = bnsum[c] * inv;
    float var  = bnsq[c] * inv - mean * mean;
    float scale = rsqrtf(var + EPSV) * gamma[c];
    float shift = beta[c] - mean * scale;

    const short* p = h2seq + (size_t)b*HH + c;    // [t][b][h]
    float acc = 0.f;
    #pragma unroll 4
    for (int t = 0; t < TT; ++t) {
        float v = bf2f(p[(size_t)t*BB*HH]) * scale + shift;
        v = fminf(fmaxf(v, -2.f), 2.f);
        acc += v;
    }
    summ[c] = acc * (1.f / TT);
    __syncthreads();
    if (c < OUTD) {
        float d = fcb[c];
        const float* wr = fcw + c*HH;
        #pragma unroll 8
        for (int h = 0; h < HH; ++h) d += wr[h] * summ[h];
        out[b*OUTD + c] = d;
    }
}

extern "C" void kernel_launch(void* const* d_in, const int* in_sizes, int n_in,
                              void* d_out, int out_size, void* d_ws, size_t ws_size,
                              hipStream_t stream)
{
    const float* x    = (const float*)d_in[0];
    const float* wih1 = (const float*)d_in[1];
    const float* whh1 = (const float*)d_in[2];
    const float* bih1 = (const float*)d_in[3];
    const float* bhh1 = (const float*)d_in[4];
    const float* wih2 = (const float*)d_in[5];
    const float* whh2 = (const float*)d_in[6];
    const float* bih2 = (const float*)d_in[7];
    const float* bhh2 = (const float*)d_in[8];
    const float* gamma= (const float*)d_in[9];
    const float* beta = (const float*)d_in[10];
    const float* fcw  = (const float*)d_in[11];
    const float* fcb  = (const float*)d_in[12];
    char* ws = (char*)d_ws;

    // progress counters + BN accumulators start at 0 (re-zeroed every replay)
    (void)hipMemsetAsync(ws, 0, OFF_ZERO_END, stream);

    // 32 clusters x 4 stages = 128 co-resident WGs (one per CU)
    hipLaunchKernelGGL(gru_pipe, dim3(NCL*4), dim3(512), 0, stream,
                       x, wih1, whh1, bih1, bhh1, wih2, whh2, bih2, bhh2, ws);

    hipLaunchKernelGGL(gru_final, dim3(BB), dim3(HH), 0, stream,
                       (const char*)ws, gamma, beta, fcw, fcb, (float*)d_out);
}